// Round 1
// 607.092 us; speedup vs baseline: 1.1704x; 1.1704x over previous
//
#include <hip/hip_runtime.h>

#define N_NODES 100000
#define N_EDGES 3200000
#define D 256
#define OVF_MAX 8192

#define RPB 256                    // rows per bucket
#define NBUCK 391                  // ceil(N_NODES / RPB)
#define CAPB 11264                 // bucket capacity (mean 8192, +34 sigma)

#define CHUNK 4096                 // edges per bin block (32 KB LDS staging)
#define NBLK_A ((N_EDGES + CHUNK - 1) / CHUNK)   // 782

#define GEMM_BLOCKS (N_NODES / 16)               // 6250
#define SCAP 9216                  // LDS-staged records per bucket (+11 sigma)

typedef __attribute__((ext_vector_type(8))) short bf16x8;
typedef __attribute__((ext_vector_type(4))) float f32x4;
typedef __attribute__((ext_vector_type(2))) float f32x2;

// ---------------- static device scratch (rebuilt every call) ----------------
// W^T packed MFMA-fragment-contiguous: [ntile16][kstep8][lane64][8 bf16]
__device__ unsigned short g_wtp[(size_t)16 * 8 * 64 * 8];   // 128 KB
__device__ unsigned short g_support[(size_t)N_NODES * D];   // 51.2 MB bf16
__device__ int   g_bucket_cur[NBUCK];
__device__ int2  g_binned[(size_t)NBUCK * CAPB];            // 35.2 MB
__device__ int   g_novf;
__device__ int   g_ovf_row[OVF_MAX];
__device__ int2  g_ovf_edge[OVF_MAX];

// fp32 -> bf16 round-to-nearest-even
__device__ __forceinline__ unsigned short f2bf(float f) {
    unsigned u = __float_as_uint(f);
    unsigned r = u + 0x7fffu + ((u >> 16) & 1u);
    return (unsigned short)(r >> 16);
}

// ---------------------------------- setup: pack W^T bf16 + zero cursors
// packed index p = ((nt*8 + s)*64 + lane)*8 + i :
//   n = nt*16 + (lane&15), k = s*32 + (lane>>4)*8 + i  -> source W[k][n]
__global__ void setup_kernel(const float* __restrict__ W) {
    const int tid = threadIdx.x;
    if (blockIdx.x < 64) {
        int pb = (blockIdx.x * 256 + tid) * 4;
        #pragma unroll
        for (int j = 0; j < 4; ++j) {
            int p    = pb + j;
            int i8   = p & 7;
            int lane = (p >> 3) & 63;
            int s    = (p >> 9) & 7;
            int nt   = p >> 12;
            int n = nt * 16 + (lane & 15);
            int k = s * 32 + (lane >> 4) * 8 + i8;
            g_wtp[p] = f2bf(W[(size_t)k * D + n]);
        }
    }
    for (int i = blockIdx.x * blockDim.x + tid; i < NBUCK;
         i += gridDim.x * blockDim.x)
        g_bucket_cur[i] = 0;
    if (blockIdx.x == 0 && tid == 0) g_novf = 0;
}

// -------------------- fused: bin (no dep on x,W) || MFMA GEMM (no dep on edges)
union SmemK2 {
    struct {
        int2 rec[CHUNK];           // 32 KB staging
        int  cnt[NBUCK];
        int  pre[NBUCK + 1];
        int  bas[NBUCK];
    } bin;                         // ~37 KB
    float tile[4][16][68];         // 17.4 KB
};

__launch_bounds__(256)
__global__ void bin_gemm_kernel(const float* __restrict__ x,
                                const float* __restrict__ edge_val,
                                const int* __restrict__ edge_row,
                                const int* __restrict__ edge_col) {
    __shared__ SmemK2 sm;
    const int tid = threadIdx.x;
    const int b = blockIdx.x;

    if (b < NBLK_A) {
        // ---------------- phase A: bin by row>>8 (bucket-sorted LDS + bursts)
        auto& B = sm.bin;
        const int e0 = b * CHUNK;
        for (int q = tid; q < NBUCK; q += 256) B.cnt[q] = 0;
        __syncthreads();
        #pragma unroll
        for (int j = 0; j < CHUNK / 256; ++j) {
            int e = e0 + tid + j * 256;
            if (e < N_EDGES) atomicAdd(&B.cnt[edge_row[e] >> 8], 1);
        }
        __syncthreads();
        if (tid == 0) {
            int run = 0;
            for (int q = 0; q < NBUCK; ++q) { B.pre[q] = run; run += B.cnt[q]; }
            B.pre[NBUCK] = run;
        }
        __syncthreads();
        for (int q = tid; q < NBUCK; q += 256)
            B.bas[q] = B.cnt[q] ? atomicAdd(&g_bucket_cur[q], B.cnt[q]) : 0;
        __syncthreads();
        for (int q = tid; q < NBUCK; q += 256) B.cnt[q] = 0;  // reuse as offsets
        __syncthreads();
        #pragma unroll
        for (int j = 0; j < CHUNK / 256; ++j) {
            int e = e0 + tid + j * 256;
            if (e < N_EDGES) {
                int r = edge_row[e];
                int q = r >> 8;
                int o = atomicAdd(&B.cnt[q], 1);
                int2 pk;
                pk.x = edge_col[e] | ((r & 255) << 17);   // col:17b | row_local:8b
                pk.y = __float_as_int(edge_val[e]);
                B.rec[B.pre[q] + o] = pk;
            }
        }
        __syncthreads();
        const int total = B.pre[NBUCK];
        for (int i = tid; i < total; i += 256) {
            int lo = 0, hi = NBUCK;
            while (hi - lo > 1) {
                int mid = (lo + hi) >> 1;
                if (B.pre[mid] <= i) lo = mid; else hi = mid;
            }
            int q = lo;
            int dest = B.bas[q] + (i - B.pre[q]);
            int2 pk = B.rec[i];
            if (dest < CAPB) {
                g_binned[(size_t)q * CAPB + dest] = pk;
            } else {
                int o = atomicAdd(&g_novf, 1);
                if (o < OVF_MAX) {
                    g_ovf_row[o] = (q << 8) | (pk.x >> 17);
                    int2 ov; ov.x = pk.x & 0x1FFFF; ov.y = pk.y;
                    g_ovf_edge[o] = ov;
                }
            }
        }
    } else {
        // ---------------- GEMM: per-wave 16x64 tile, K=256, packed-B coalesced
        const int g    = b - NBLK_A;
        const int wave = tid >> 6;
        const int lane = tid & 63;
        const int m0   = g * 16;
        const int n0   = wave * 64;
        const int lm   = lane & 15;
        const int q    = lane >> 4;

        f32x4 acc0 = {}, acc1 = {}, acc2 = {}, acc3 = {};

        #pragma unroll
        for (int s = 0; s < 8; ++s) {
            const int k0 = s * 32;
            const float* Arow = &x[(size_t)(m0 + lm) * D + k0 + q * 8];
            float4 f0 = *(const float4*)&Arow[0];
            float4 f1 = *(const float4*)&Arow[4];
            union { bf16x8 v; unsigned short u[8]; } au;
            au.u[0] = f2bf(f0.x); au.u[1] = f2bf(f0.y);
            au.u[2] = f2bf(f0.z); au.u[3] = f2bf(f0.w);
            au.u[4] = f2bf(f1.x); au.u[5] = f2bf(f1.y);
            au.u[6] = f2bf(f1.z); au.u[7] = f2bf(f1.w);

            // packed: ((wave*4 + j)*8 + s)*64*8 + lane*8 — 1 KB burst per load
            const unsigned short* bp =
                &g_wtp[((size_t)(wave * 4) * 8 + s) * 512 + lane * 8];
            bf16x8 b0 = *(const bf16x8*)&bp[0 * 4096];
            bf16x8 b1 = *(const bf16x8*)&bp[1 * 4096];
            bf16x8 b2 = *(const bf16x8*)&bp[2 * 4096];
            bf16x8 b3 = *(const bf16x8*)&bp[3 * 4096];
            acc0 = __builtin_amdgcn_mfma_f32_16x16x32_bf16(au.v, b0, acc0, 0, 0, 0);
            acc1 = __builtin_amdgcn_mfma_f32_16x16x32_bf16(au.v, b1, acc1, 0, 0, 0);
            acc2 = __builtin_amdgcn_mfma_f32_16x16x32_bf16(au.v, b2, acc2, 0, 0, 0);
            acc3 = __builtin_amdgcn_mfma_f32_16x16x32_bf16(au.v, b3, acc3, 0, 0, 0);
        }

        #pragma unroll
        for (int r = 0; r < 4; ++r) {
            sm.tile[wave][q * 4 + r][ 0 + lm] = acc0[r];
            sm.tile[wave][q * 4 + r][16 + lm] = acc1[r];
            sm.tile[wave][q * 4 + r][32 + lm] = acc2[r];
            sm.tile[wave][q * 4 + r][48 + lm] = acc3[r];
        }
        const int row  = lane >> 2;
        const int cseg = (lane & 3) * 16;
        unsigned short outv[16];
        #pragma unroll
        for (int j = 0; j < 16; ++j)
            outv[j] = f2bf(sm.tile[wave][row][cseg + j]);
        unsigned short* dst = &g_support[(size_t)(m0 + row) * D + n0 + cseg];
        *(uint4*)&dst[0] = *(const uint4*)&outv[0];
        *(uint4*)&dst[8] = *(const uint4*)&outv[8];
    }
}

// ---------------------------------------------------------------- SpMM
// One 1024-thread block per bucket: counting-sort the bucket's records by
// row_local in LDS (replaces the padded-CSR fill + g_pad round-trip), then
// 8 groups x 128 threads run the gather loop; group g owns rows g*32..g*32+31.
__launch_bounds__(1024)
__global__ void spmm_kernel(float* __restrict__ out) {
    __shared__ int2 srec[SCAP];          // 73.7 KB
    __shared__ int rcnt[RPB];
    __shared__ int rofs[RPB];
    __shared__ int rcur[RPB];
    const int k   = blockIdx.x;
    const int tid = threadIdx.x;
    const int nrec_all = min(g_bucket_cur[k], CAPB);
    const int nstage   = min(nrec_all, SCAP);
    const int2* src = &g_binned[(size_t)k * CAPB];

    for (int i = tid; i < RPB; i += 1024) { rcnt[i] = 0; rcur[i] = 0; }
    __syncthreads();
    for (int i = tid; i < nstage; i += 1024)
        atomicAdd(&rcnt[src[i].x >> 17], 1);
    __syncthreads();
    if (tid < RPB) {                     // brute-force exclusive scan (256 keys)
        int s = 0;
        for (int j = 0; j < tid; ++j) s += rcnt[j];
        rofs[tid] = s;
    }
    __syncthreads();
    for (int i = tid; i < nstage; i += 1024) {
        int2 pk = src[i];
        int rl  = pk.x >> 17;
        int pos = rofs[rl] + atomicAdd(&rcur[rl], 1);
        srec[pos] = pk;
    }
    __syncthreads();

    const int grp = tid >> 7;
    const int t   = tid & 127;           // thread owns features 2t, 2t+1
    const unsigned* sup = (const unsigned*)g_support;
    const int novf = min(g_novf, OVF_MAX);

    for (int rr = 0; rr < 32; ++rr) {
        const int rl  = grp * 32 + rr;
        const int row = (k << 8) + rl;
        if (row >= N_NODES) break;
        const int cnt = rcnt[rl];
        const int ofs = rofs[rl];
        float a0 = 0.f, a1 = 0.f;
        int i = 0;
        for (; i + 3 < cnt; i += 4) {
            int2 e0 = srec[ofs + i];
            int2 e1 = srec[ofs + i + 1];
            int2 e2 = srec[ofs + i + 2];
            int2 e3 = srec[ofs + i + 3];
            unsigned p0 = sup[(size_t)(e0.x & 0x1FFFF) * (D / 2) + t];
            unsigned p1 = sup[(size_t)(e1.x & 0x1FFFF) * (D / 2) + t];
            unsigned p2 = sup[(size_t)(e2.x & 0x1FFFF) * (D / 2) + t];
            unsigned p3 = sup[(size_t)(e3.x & 0x1FFFF) * (D / 2) + t];
            float v0 = __int_as_float(e0.y);
            float v1 = __int_as_float(e1.y);
            float v2 = __int_as_float(e2.y);
            float v3 = __int_as_float(e3.y);
            a0 += v0 * __uint_as_float(p0 << 16);
            a1 += v0 * __uint_as_float(p0 & 0xffff0000u);
            a0 += v1 * __uint_as_float(p1 << 16);
            a1 += v1 * __uint_as_float(p1 & 0xffff0000u);
            a0 += v2 * __uint_as_float(p2 << 16);
            a1 += v2 * __uint_as_float(p2 & 0xffff0000u);
            a0 += v3 * __uint_as_float(p3 << 16);
            a1 += v3 * __uint_as_float(p3 & 0xffff0000u);
        }
        for (; i < cnt; ++i) {
            int2 e0 = srec[ofs + i];
            unsigned p0 = sup[(size_t)(e0.x & 0x1FFFF) * (D / 2) + t];
            float v0 = __int_as_float(e0.y);
            a0 += v0 * __uint_as_float(p0 << 16);
            a1 += v0 * __uint_as_float(p0 & 0xffff0000u);
        }
        // tail: records that didn't fit the LDS stage (usually none)
        for (int j = nstage; j < nrec_all; ++j) {
            int2 pk = src[j];
            if ((pk.x >> 17) == rl) {
                unsigned p0 = sup[(size_t)(pk.x & 0x1FFFF) * (D / 2) + t];
                float v0 = __int_as_float(pk.y);
                a0 += v0 * __uint_as_float(p0 << 16);
                a1 += v0 * __uint_as_float(p0 & 0xffff0000u);
            }
        }
        // bucket-overflow fallback (empty in practice)
        if (novf > 0) {
            for (int j = 0; j < novf; ++j) {
                if (g_ovf_row[j] == row) {
                    int2 ee = g_ovf_edge[j];
                    float v0 = __int_as_float(ee.y);
                    unsigned p0 = sup[(size_t)ee.x * (D / 2) + t];
                    a0 += v0 * __uint_as_float(p0 << 16);
                    a1 += v0 * __uint_as_float(p0 & 0xffff0000u);
                }
            }
        }
        f32x2 o;
        o.x = fmaxf(a0, 0.f);
        o.y = fmaxf(a1, 0.f);
        __builtin_nontemporal_store(o, (f32x2*)&out[(size_t)row * D + 2 * t]);
    }
}

// ---------------------------------------------------------------- launcher
extern "C" void kernel_launch(void* const* d_in, const int* in_sizes, int n_in,
                              void* d_out, int out_size, void* d_ws, size_t ws_size,
                              hipStream_t stream) {
    const float* x        = (const float*)d_in[0];
    const float* weight   = (const float*)d_in[1];
    const float* edge_val = (const float*)d_in[2];
    const int*   edge_row = (const int*)d_in[3];
    const int*   edge_col = (const int*)d_in[4];
    float* out = (float*)d_out;

    setup_kernel<<<64, 256, 0, stream>>>(weight);
    bin_gemm_kernel<<<NBLK_A + GEMM_BLOCKS, 256, 0, stream>>>(x, edge_val, edge_row, edge_col);
    spmm_kernel<<<NBUCK, 1024, 0, stream>>>(out);
}